// Round 7
// baseline (199.098 us; speedup 1.0000x reference)
//
#include <hip/hip_runtime.h>
#include <stdint.h>

// Problem constants
constexpr int T = 2048;
constexpr int B = 8;
constexpr int C = 1024;
constexpr int H = 16;
constexpr int K = 31;
constexpr int BC = B * C;          // 8192 columns (b,c); stride between times

// Tiling: block = 64 channels (ONE head) x 64 time steps, LDS-staged.
constexpr int HALO = 32;           // K-1=30 rounded to 4-row DMA granularity
constexpr int TT = 64;             // time steps per block
constexpr int NR = TT + HALO;      // 96 LDS rows
constexpr int CW = 64;             // channel columns per block
constexpr int BLOCK = 256;
constexpr int TPT = 4;             // times per thread (TT / 16 t-groups)
constexpr int NCOLG = BC / CW;     // 128 column groups
constexpr int NTCH = T / TT;       // 32 time chunks
constexpr int NBLK = NCOLG * NTCH; // 4096 blocks
constexpr int NDMA = NR / 4;       // 24 global_load_lds per block (1KB each)

typedef const __attribute__((address_space(1))) uint32_t gas_u32;
typedef __attribute__((address_space(3))) uint32_t las_u32;
typedef float f32x4 __attribute__((ext_vector_type(4)));

// ---------------------------------------------------------------------------
// out[t,col] = sum_{k=0..30} ws[k] * x[t-30+k, col] + bias[c]
// ws = softmax(w[head]); head is block-uniform (CW == G == 64).
// Tile row r holds global time t0 - HALO + r for the block's 64 columns.
// ---------------------------------------------------------------------------
__global__ __launch_bounds__(BLOCK, 6) void lconv_tbc_kernel(
        const float* __restrict__ x,
        const float* __restrict__ w,
        const float* __restrict__ bias,
        float* __restrict__ out) {
    __shared__ float tile[NR][CW];   // 24 KiB -> 6 blocks/CU

    const int tid = threadIdx.x;
    const int wid = tid >> 6;
    const int lane = tid & 63;
    const int colg = blockIdx.x & (NCOLG - 1);   // 0..127
    const int tch = blockIdx.x >> 7;             // 0..31
    const int col0 = colg * CW;
    const int t0 = tch * TT;
    const int cblk = col0 & (C - 1);             // channel base within C
    const int h = cblk >> 6;                     // head, block-uniform

    // ---- DMA issue (before any VALU work): wave w does instrs w*6..w*6+5.
    // Instr i fills rows 4i..4i+3 (1KB): HW dest = uniform base + lane*16.
    // Per-lane source: lane l -> row 4i + (l>>4), cols (l&15)*4..+3.
    const int lrow = lane >> 4;
    const int lc4 = (lane & 15) * 4;
    const float* src0 = x + (t0 - HALO) * BC + col0 + lrow * BC + lc4;
    #pragma unroll
    for (int ii = 0; ii < NDMA / 4; ++ii) {
        const int i = wid * (NDMA / 4) + ii;
        if (t0 - HALO + 4 * i >= 0) {            // uniform condition
            __builtin_amdgcn_global_load_lds(
                (gas_u32*)(src0 + 4 * i * BC),
                (las_u32*)&tile[4 * i][0], 16, 0, 0);
        }
    }
    // Causal zero padding: only t-chunk 0 skips DMA for rows 0..31.
    if (t0 == 0) {
        #pragma unroll
        for (int j = 0; j < 8; ++j)
            ((float*)tile)[tid * 8 + j] = 0.0f;  // rows 0..31 exactly
    }

    // ---- Per-wave softmax of the head's taps (overlaps DMA; VALU/SALU).
    float wv[K];
    float m = -1e30f;
    #pragma unroll
    for (int k = 0; k < K; ++k) {
        wv[k] = w[h * K + k];                    // uniform -> scalar loads
        m = fmaxf(m, wv[k]);
    }
    float s = 0.0f;
    #pragma unroll
    for (int k = 0; k < K; ++k) {
        wv[k] = __expf(wv[k] - m);
        s += wv[k];
    }
    const float inv = 1.0f / s;
    float ws[K];                                 // forced wave-uniform -> SGPR
    #pragma unroll
    for (int k = 0; k < K; ++k)
        ws[k] = __uint_as_float(
            __builtin_amdgcn_readfirstlane(__float_as_uint(wv[k] * inv)));

    const int cg = tid & 15;                     // c-group (4 channels)
    const int tg = tid >> 4;                     // t-group (4 times)
    const int c4 = cg * 4;
    const f32x4 bi = *(const f32x4*)&bias[cblk + c4];

    __syncthreads();   // tile resident (vmcnt/lgkm drained by barrier)

    // ---- d-major accumulation: 34 ds_read_b128 (imm offsets), acc stays
    // small (4 x f32x4) so no register-pressure war with the scheduler.
    float acc0x = bi.x, acc0y = bi.y, acc0z = bi.z, acc0w = bi.w;
    f32x4 acc[TPT];
    #pragma unroll
    for (int u = 0; u < TPT; ++u) acc[u] = bi;

    const float* trow = &tile[4 * tg + 2][c4];   // row j -> +j*64 floats
    #pragma unroll
    for (int j = 0; j < TPT + K - 1; ++j) {      // 34 rows
        const f32x4 r = *(const f32x4*)(trow + j * CW);
        #pragma unroll
        for (int u = 0; u < TPT; ++u) {
            const int k = j - u;
            if (k >= 0 && k < K) {
                acc[u].x = fmaf(ws[k], r.x, acc[u].x);
                acc[u].y = fmaf(ws[k], r.y, acc[u].y);
                acc[u].z = fmaf(ws[k], r.z, acc[u].z);
                acc[u].w = fmaf(ws[k], r.w, acc[u].w);
            }
        }
    }

    // ---- 4 x dwordx4 nontemporal stores (16B/lane).
    const int obase = (t0 + 4 * tg) * BC + col0 + c4;
    #pragma unroll
    for (int u = 0; u < TPT; ++u)
        __builtin_nontemporal_store(acc[u], (f32x4*)(out + obase + u * BC));
}

extern "C" void kernel_launch(void* const* d_in, const int* in_sizes, int n_in,
                              void* d_out, int out_size, void* d_ws, size_t ws_size,
                              hipStream_t stream) {
    const float* x = (const float*)d_in[0];      // [T, B, C]
    const float* w = (const float*)d_in[1];      // [H, 1, K]
    const float* bias = (const float*)d_in[2];   // [C]
    float* out = (float*)d_out;                  // [T, B, C]

    lconv_tbc_kernel<<<dim3(NBLK), dim3(BLOCK), 0, stream>>>(x, w, bias, out);
}